// Round 6
// baseline (425.130 us; speedup 1.0000x reference)
//
#include <hip/hip_runtime.h>

#define B_ 64
#define C_ 1024
#define Q_ 128
#define H_ 256

typedef __attribute__((ext_vector_type(8))) short bfrag;   // 8 x bf16
typedef __attribute__((ext_vector_type(4))) float f32x4;

__device__ __forceinline__ short f2bf(float f) {
    union { float f; unsigned u; } v; v.f = f;
    unsigned u = v.u;
    unsigned r = u + 0x7fffu + ((u >> 16) & 1u);
    return (short)(r >> 16);
}
__device__ __forceinline__ float bf2f(short s) {
    union { float f; unsigned u; } v;
    v.u = ((unsigned)(unsigned short)s) << 16;
    return v.f;
}

// ---------------- K_prep: qh/ql bf16 [B,Q,H], qT bf16 [B,H,Q], qdot --------
__global__ __launch_bounds__(256) void k_prep(
    const float* __restrict__ qry, const float* __restrict__ attw,
    const float* __restrict__ attb,
    short* __restrict__ qh, short* __restrict__ ql, short* __restrict__ qT,
    float* __restrict__ qdot)
{
    __shared__ float wq_s[H_];
    __shared__ short t_s[64][80];
    const int tid = threadIdx.x;
    const int bid = blockIdx.x;          // 0..127
    const int b = bid >> 1;
    const int q0 = (bid & 1) * 64;
    wq_s[tid] = attw[H_ + tid];
    __syncthreads();

    const int rloc = tid >> 2;           // 0..63
    const int row = q0 + rloc;
    const int colseg = (tid & 3) * 16;
    const float* src_base = qry + ((size_t)b * Q_ + row) * H_;
    float qp = 0.f;

    for (int ct = 0; ct < 4; ++ct) {
        const int c0 = ct * 64;
        float tv[16];
        *(f32x4*)&tv[0]  = *(const f32x4*)(src_base + c0 + colseg);
        *(f32x4*)&tv[4]  = *(const f32x4*)(src_base + c0 + colseg + 4);
        *(f32x4*)&tv[8]  = *(const f32x4*)(src_base + c0 + colseg + 8);
        *(f32x4*)&tv[12] = *(const f32x4*)(src_base + c0 + colseg + 12);
        bfrag hv0, lv0, hv1, lv1;
        #pragma unroll
        for (int j = 0; j < 8; ++j) {
            qp += tv[j] * wq_s[c0 + colseg + j];
            short hi = f2bf(tv[j]);
            hv0[j] = hi; lv0[j] = f2bf(tv[j] - bf2f(hi));
        }
        #pragma unroll
        for (int j = 0; j < 8; ++j) {
            float t = tv[8 + j];
            qp += t * wq_s[c0 + colseg + 8 + j];
            short hi = f2bf(t);
            hv1[j] = hi; lv1[j] = f2bf(t - bf2f(hi));
        }
        short* qh_p = qh + ((size_t)b * Q_ + row) * H_ + c0 + colseg;
        *(bfrag*)qh_p = hv0; *(bfrag*)(qh_p + 8) = hv1;
        short* ql_p = ql + ((size_t)b * Q_ + row) * H_ + c0 + colseg;
        *(bfrag*)ql_p = lv0; *(bfrag*)(ql_p + 8) = lv1;
        // transpose hi into t_s[h_local][q_local]
        #pragma unroll
        for (int j = 0; j < 8; ++j) {
            t_s[colseg + j][rloc] = hv0[j];
            t_s[colseg + 8 + j][rloc] = hv1[j];
        }
        __syncthreads();
        {
            // write-back BOTH 8-wide halves: q_local qs..qs+15 (coverage fix)
            const int hl = tid >> 2;         // 0..63
            const int qs = (tid & 3) * 16;
            bfrag tv2 = *(bfrag*)&t_s[hl][qs];
            bfrag tv3 = *(bfrag*)&t_s[hl][qs + 8];
            short* dst = &qT[((size_t)b * H_ + c0 + hl) * Q_ + q0 + qs];
            *(bfrag*)dst = tv2;
            *(bfrag*)(dst + 8) = tv3;
        }
        __syncthreads();
    }
    qp += __shfl_xor(qp, 1);
    qp += __shfl_xor(qp, 2);
    if ((tid & 3) == 0) qdot[b * Q_ + row] = qp + attb[0];
}

// ---------------- K0 (fallback): qdot -------------------------------------
__global__ __launch_bounds__(256) void k_qdot(
    const float* __restrict__ qry, const float* __restrict__ attw,
    const float* __restrict__ attb, float* __restrict__ qdot)
{
    const int tid = threadIdx.x, lane = tid & 63, w = tid >> 6;
    const int bid = blockIdx.x;
    const int b = bid >> 5, qg = bid & 31;
    const int q = qg * 4 + w;
    const float* src = qry + ((size_t)b * Q_ + q) * H_ + lane * 4;
    f32x4 v = *(const f32x4*)src;
    f32x4 wv = *(const f32x4*)(attw + H_ + lane * 4);
    float p = v.x * wv.x + v.y * wv.y + v.z * wv.z + v.w * wv.w;
    #pragma unroll
    for (int d = 1; d < 64; d <<= 1) p += __shfl_xor(p, d);
    if (lane == 0) qdot[b * Q_ + q] = p + attb[0];
}

#define SPAD 40    // k-slice row stride (32 + 8 pad)
#define PPAD 136   // P row stride (128 + 8 pad)
#define APAD 268   // a_s row stride (256 + 12 pad)

// ---------------- K1 fast: sim -> softmax -> a ; out cols 0..2, smax ------
__global__ __launch_bounds__(256) void k_sim(
    const float* __restrict__ ctx,
    const short* __restrict__ qh_g,
    const short* __restrict__ ql_g,
    const short* __restrict__ qT,
    const float* __restrict__ attw,
    const float* __restrict__ qdot,
    float* __restrict__ smax,
    float* __restrict__ out)
{
    __shared__ union SM {
        struct {
            short qh[Q_][SPAD];
            short ql[Q_][SPAD];
            short ch[64][SPAD];
            short cl[64][SPAD];
        } st;
        float a_s[16][APAD];
    } u;
    __shared__ short P_s[64][PPAD];
    __shared__ float wm_s[H_];
    __shared__ float wc_s[H_];
    __shared__ float qd_s[Q_];
    __shared__ float cdot_s[64];

    const int tid = threadIdx.x;
    const int lane = tid & 63;
    const int w = tid >> 6;
    const int bid = blockIdx.x;
    const int b = bid >> 4;
    const int c0 = (bid & 15) * 64;

    wc_s[tid] = attw[tid];
    wm_s[tid] = attw[2 * H_ + tid];
    if (tid < Q_) qd_s[tid] = qdot[b * Q_ + tid];
    __syncthreads();

    const int r16 = lane & 15;
    const int kp  = lane >> 4;

    f32x4 acc[8];
    #pragma unroll
    for (int t = 0; t < 8; ++t) acc[t] = (f32x4)(0.f);

    float cdp = 0.f;

    const int crow = tid >> 2;          // 0..63
    const int ckof = (tid & 3) * 8;     // 0,8,16,24
    const int qrow = tid >> 1;          // 0..127
    const int qkof = (tid & 1) * 16;    // 0,16

    const float* ctxb = ctx + ((size_t)b * C_ + c0) * H_;
    const short* qhb = qh_g + (size_t)b * Q_ * H_;
    const short* qlb = ql_g + (size_t)b * Q_ * H_;

    for (int k0 = 0; k0 < H_; k0 += 32) {
        // ---- stage context slice (cm = ctx*w_m, hi/lo) + cdot partial ----
        {
            const float* src = ctxb + crow * H_ + k0 + ckof;
            f32x4 v0 = *(const f32x4*)(src);
            f32x4 v1 = *(const f32x4*)(src + 4);
            float tv[8];
            *(f32x4*)&tv[0] = v0;
            *(f32x4*)&tv[4] = v1;
            bfrag hv, lv;
            #pragma unroll
            for (int j = 0; j < 8; ++j) {
                int k = k0 + ckof + j;
                cdp += tv[j] * wc_s[k];
                float cm = tv[j] * wm_s[k];
                short hi = f2bf(cm);
                hv[j] = hi;
                lv[j] = f2bf(cm - bf2f(hi));
            }
            *(bfrag*)&u.st.ch[crow][ckof] = hv;
            *(bfrag*)&u.st.cl[crow][ckof] = lv;
        }
        // ---- stage query slice: BOTH 8-short halves per thread ----
        {
            const short* qhp = &qhb[qrow * H_ + k0 + qkof];
            const short* qlp = &qlb[qrow * H_ + k0 + qkof];
            *(bfrag*)&u.st.qh[qrow][qkof]     = *(const bfrag*)qhp;
            *(bfrag*)&u.st.qh[qrow][qkof + 8] = *(const bfrag*)(qhp + 8);
            *(bfrag*)&u.st.ql[qrow][qkof]     = *(const bfrag*)qlp;
            *(bfrag*)&u.st.ql[qrow][qkof + 8] = *(const bfrag*)(qlp + 8);
        }
        __syncthreads();
        // ---- MFMA: sim tiles (hh + lh + hl) ----
        bfrag a_hi = *(bfrag*)&u.st.ch[w * 16 + r16][kp * 8];
        bfrag a_lo = *(bfrag*)&u.st.cl[w * 16 + r16][kp * 8];
        #pragma unroll
        for (int t = 0; t < 8; ++t) {
            bfrag b_hi = *(bfrag*)&u.st.qh[t * 16 + r16][kp * 8];
            bfrag b_lo = *(bfrag*)&u.st.ql[t * 16 + r16][kp * 8];
            acc[t] = __builtin_amdgcn_mfma_f32_16x16x32_bf16(a_hi, b_hi, acc[t], 0, 0, 0);
            acc[t] = __builtin_amdgcn_mfma_f32_16x16x32_bf16(a_lo, b_hi, acc[t], 0, 0, 0);
            acc[t] = __builtin_amdgcn_mfma_f32_16x16x32_bf16(a_hi, b_lo, acc[t], 0, 0, 0);
        }
        __syncthreads();
    }

    // ---- cdot reduce ----
    {
        float cv = cdp;
        cv += __shfl_xor(cv, 1);
        cv += __shfl_xor(cv, 2);
        if ((lane & 3) == 0) cdot_s[crow] = cv;
    }
    __syncthreads();

    // ---- softmax over q ----
    float qdv[8];
    #pragma unroll
    for (int t = 0; t < 8; ++t) qdv[t] = qd_s[t * 16 + r16];
    float cdv[4];
    #pragma unroll
    for (int r = 0; r < 4; ++r) cdv[r] = cdot_s[w * 16 + kp * 4 + r];

    #pragma unroll
    for (int r = 0; r < 4; ++r) {
        float ev[8];
        float m = -1e30f;
        #pragma unroll
        for (int t = 0; t < 8; ++t) {
            float s = acc[t][r] + cdv[r] + qdv[t];
            ev[t] = s;
            m = fmaxf(m, s);
        }
        m = fmaxf(m, __shfl_xor(m, 1));
        m = fmaxf(m, __shfl_xor(m, 2));
        m = fmaxf(m, __shfl_xor(m, 4));
        m = fmaxf(m, __shfl_xor(m, 8));
        float ssum = 0.f;
        #pragma unroll
        for (int t = 0; t < 8; ++t) {
            float e = __expf(ev[t] - m);
            ev[t] = e;
            ssum += e;
        }
        ssum += __shfl_xor(ssum, 1);
        ssum += __shfl_xor(ssum, 2);
        ssum += __shfl_xor(ssum, 4);
        ssum += __shfl_xor(ssum, 8);
        const int rr = w * 16 + kp * 4 + r;
        if (r16 == 0) smax[(size_t)b * C_ + c0 + rr] = m;
        float inv = 1.f / ssum;
        #pragma unroll
        for (int t = 0; t < 8; ++t)
            P_s[rr][t * 16 + r16] = f2bf(ev[t] * inv);
    }
    __syncthreads();

    // ---- a = P @ query, B-frags from precomputed qT (bf16, 16B loads) ----
    f32x4 a2[4][4];
    #pragma unroll
    for (int m = 0; m < 4; ++m)
        #pragma unroll
        for (int i = 0; i < 4; ++i) a2[m][i] = (f32x4)(0.f);

    const int h0w = w * 64;
    const short* qTb = qT + (size_t)b * H_ * Q_;
    #pragma unroll
    for (int kq = 0; kq < 4; ++kq) {
        bfrag ap[4];
        #pragma unroll
        for (int m = 0; m < 4; ++m)
            ap[m] = *(bfrag*)&P_s[m * 16 + r16][kq * 32 + kp * 8];
        #pragma unroll
        for (int i = 0; i < 4; ++i) {
            bfrag bq = *(const bfrag*)&qTb[(size_t)(h0w + i * 16 + r16) * Q_ + kq * 32 + kp * 8];
            #pragma unroll
            for (int m = 0; m < 4; ++m)
                a2[m][i] = __builtin_amdgcn_mfma_f32_16x16x32_bf16(ap[m], bq, a2[m][i], 0, 0, 0);
        }
    }

    // ---- epilogue via LDS bounce, coalesced f32x4 stores, 4 quarters ----
    #pragma unroll
    for (int m = 0; m < 4; ++m) {
        #pragma unroll
        for (int i = 0; i < 4; ++i)
            #pragma unroll
            for (int r = 0; r < 4; ++r)
                u.a_s[kp * 4 + r][w * 64 + i * 16 + r16] = a2[m][i][r];
        __syncthreads();
        {
            const int row = tid >> 4;        // 0..15
            const int seg = tid & 15;        // h = seg*16
            const int cl = m * 16 + row;
            const size_t orow = ((size_t)b * C_ + c0 + cl) * (4 * H_);
            const float* cp = ctxb + (size_t)cl * H_ + seg * 16;
            float* op = out + orow + seg * 16;
            #pragma unroll
            for (int k2 = 0; k2 < 4; ++k2) {
                f32x4 cvx = *(const f32x4*)(cp + k2 * 4);
                f32x4 av = *(const f32x4*)&u.a_s[row][seg * 16 + k2 * 4];
                *(f32x4*)(op + k2 * 4) = cvx;
                *(f32x4*)(op + H_ + k2 * 4) = av;
                *(f32x4*)(op + 2 * H_ + k2 * 4) = cvx * av;
            }
        }
        __syncthreads();
    }
}

// ---------------- K1 fallback (round-1 version, fp32 inputs) ---------------
__global__ __launch_bounds__(256) void k_sim_v1(
    const float* __restrict__ ctx, const float* __restrict__ qry,
    const float* __restrict__ attw, const float* __restrict__ qdot,
    float* __restrict__ smax, float* __restrict__ out)
{
    __shared__ float wm_s[H_];
    __shared__ float wc_s[H_];
    __shared__ float qd_s[Q_];
    __shared__ float cdot_s[64];
    __shared__ short qh_s[Q_][SPAD];
    __shared__ short ql_s[Q_][SPAD];
    __shared__ short ch_s[64][SPAD];
    __shared__ short cl_s[64][SPAD];
    __shared__ short P_s[64][PPAD];

    const int tid = threadIdx.x;
    const int lane = tid & 63;
    const int w = tid >> 6;
    const int bid = blockIdx.x;
    const int b = bid >> 4;
    const int c0 = (bid & 15) * 64;

    wc_s[tid] = attw[tid];
    wm_s[tid] = attw[2 * H_ + tid];
    if (tid < Q_) qd_s[tid] = qdot[b * Q_ + tid];
    __syncthreads();

    const int r16 = lane & 15;
    const int kp  = lane >> 4;

    f32x4 acc[8];
    #pragma unroll
    for (int t = 0; t < 8; ++t) acc[t] = (f32x4)(0.f);
    float cdp = 0.f;
    const int crow = tid >> 2, ckof = (tid & 3) * 8;
    const int qrow = tid >> 1, qkof = (tid & 1) * 16;
    const float* ctxb = ctx + ((size_t)b * C_ + c0) * H_;
    const float* qryb = qry + (size_t)b * Q_ * H_;

    for (int k0 = 0; k0 < H_; k0 += 32) {
        {
            const float* src = ctxb + crow * H_ + k0 + ckof;
            f32x4 v0 = *(const f32x4*)(src);
            f32x4 v1 = *(const f32x4*)(src + 4);
            float tv[8];
            *(f32x4*)&tv[0] = v0; *(f32x4*)&tv[4] = v1;
            bfrag hv, lv;
            #pragma unroll
            for (int j = 0; j < 8; ++j) {
                int k = k0 + ckof + j;
                cdp += tv[j] * wc_s[k];
                float cm = tv[j] * wm_s[k];
                short hi = f2bf(cm);
                hv[j] = hi; lv[j] = f2bf(cm - bf2f(hi));
            }
            *(bfrag*)&ch_s[crow][ckof] = hv;
            *(bfrag*)&cl_s[crow][ckof] = lv;
        }
        {
            const float* src = qryb + qrow * H_ + k0 + qkof;
            float tv[16];
            *(f32x4*)&tv[0]  = *(const f32x4*)(src);
            *(f32x4*)&tv[4]  = *(const f32x4*)(src + 4);
            *(f32x4*)&tv[8]  = *(const f32x4*)(src + 8);
            *(f32x4*)&tv[12] = *(const f32x4*)(src + 12);
            bfrag h0v, l0v, h1v, l1v;
            #pragma unroll
            for (int j = 0; j < 8; ++j) {
                short hi = f2bf(tv[j]);
                h0v[j] = hi; l0v[j] = f2bf(tv[j] - bf2f(hi));
            }
            #pragma unroll
            for (int j = 0; j < 8; ++j) {
                short hi = f2bf(tv[8 + j]);
                h1v[j] = hi; l1v[j] = f2bf(tv[8 + j] - bf2f(hi));
            }
            *(bfrag*)&qh_s[qrow][qkof]     = h0v;
            *(bfrag*)&ql_s[qrow][qkof]     = l0v;
            *(bfrag*)&qh_s[qrow][qkof + 8] = h1v;
            *(bfrag*)&ql_s[qrow][qkof + 8] = l1v;
        }
        __syncthreads();
        bfrag a_hi = *(bfrag*)&ch_s[w * 16 + r16][kp * 8];
        bfrag a_lo = *(bfrag*)&cl_s[w * 16 + r16][kp * 8];
        #pragma unroll
        for (int t = 0; t < 8; ++t) {
            bfrag b_hi = *(bfrag*)&qh_s[t * 16 + r16][kp * 8];
            bfrag b_lo = *(bfrag*)&ql_s[t * 16 + r16][kp * 8];
            acc[t] = __builtin_amdgcn_mfma_f32_16x16x32_bf16(a_hi, b_hi, acc[t], 0, 0, 0);
            acc[t] = __builtin_amdgcn_mfma_f32_16x16x32_bf16(a_lo, b_hi, acc[t], 0, 0, 0);
            acc[t] = __builtin_amdgcn_mfma_f32_16x16x32_bf16(a_hi, b_lo, acc[t], 0, 0, 0);
        }
        __syncthreads();
    }
    {
        float cv = cdp;
        cv += __shfl_xor(cv, 1);
        cv += __shfl_xor(cv, 2);
        if ((lane & 3) == 0) cdot_s[crow] = cv;
    }
    __syncthreads();
    float qdv[8];
    #pragma unroll
    for (int t = 0; t < 8; ++t) qdv[t] = qd_s[t * 16 + r16];
    float cdv[4];
    #pragma unroll
    for (int r = 0; r < 4; ++r) cdv[r] = cdot_s[w * 16 + kp * 4 + r];
    #pragma unroll
    for (int r = 0; r < 4; ++r) {
        float ev[8];
        float m = -1e30f;
        #pragma unroll
        for (int t = 0; t < 8; ++t) {
            float s = acc[t][r] + cdv[r] + qdv[t];
            ev[t] = s; m = fmaxf(m, s);
        }
        m = fmaxf(m, __shfl_xor(m, 1));
        m = fmaxf(m, __shfl_xor(m, 2));
        m = fmaxf(m, __shfl_xor(m, 4));
        m = fmaxf(m, __shfl_xor(m, 8));
        float ssum = 0.f;
        #pragma unroll
        for (int t = 0; t < 8; ++t) {
            float e = __expf(ev[t] - m);
            ev[t] = e; ssum += e;
        }
        ssum += __shfl_xor(ssum, 1);
        ssum += __shfl_xor(ssum, 2);
        ssum += __shfl_xor(ssum, 4);
        ssum += __shfl_xor(ssum, 8);
        const int rr = w * 16 + kp * 4 + r;
        if (r16 == 0) smax[(size_t)b * C_ + c0 + rr] = m;
        float inv = 1.f / ssum;
        #pragma unroll
        for (int t = 0; t < 8; ++t)
            P_s[rr][t * 16 + r16] = f2bf(ev[t] * inv);
    }
    __syncthreads();
    f32x4 a2[4][4];
    #pragma unroll
    for (int m = 0; m < 4; ++m)
        #pragma unroll
        for (int i = 0; i < 4; ++i) a2[m][i] = (f32x4)(0.f);
    const int h0w = w * 64;
    for (int kq = 0; kq < 4; ++kq) {
        bfrag ap[4];
        #pragma unroll
        for (int m = 0; m < 4; ++m)
            ap[m] = *(bfrag*)&P_s[m * 16 + r16][kq * 32 + kp * 8];
        #pragma unroll
        for (int i = 0; i < 4; ++i) {
            const float* qc = qryb + (size_t)(kq * 32 + kp * 8) * H_ + h0w + i * 16 + r16;
            bfrag bq;
            #pragma unroll
            for (int j = 0; j < 8; ++j) bq[j] = f2bf(qc[(size_t)j * H_]);
            #pragma unroll
            for (int m = 0; m < 4; ++m)
                a2[m][i] = __builtin_amdgcn_mfma_f32_16x16x32_bf16(ap[m], bq, a2[m][i], 0, 0, 0);
        }
    }
    #pragma unroll
    for (int m = 0; m < 4; ++m) {
        #pragma unroll
        for (int r = 0; r < 4; ++r) {
            const int cl = m * 16 + kp * 4 + r;
            const size_t orow = ((size_t)b * C_ + c0 + cl) * (4 * H_);
            const float* crow_p = ctxb + (size_t)cl * H_;
            #pragma unroll
            for (int i = 0; i < 4; ++i) {
                const int h = h0w + i * 16 + r16;
                float av = a2[m][i][r];
                float cvx = crow_p[h];
                out[orow + h] = cvx;
                out[orow + H_ + h] = av;
                out[orow + 2 * H_ + h] = cvx * av;
            }
        }
    }
}

// ---------------- K2: beta softmax over C + partial b_vec ------------------
__global__ __launch_bounds__(256) void k_beta(
    const float* __restrict__ ctx, const float* __restrict__ smax,
    float* __restrict__ bpart)
{
    __shared__ float beta_s[C_];
    __shared__ float red_s[8];
    const int tid = threadIdx.x, lane = tid & 63, w = tid >> 6;
    const int bid = blockIdx.x;
    const int b = bid >> 2, quad = bid & 3;

    f32x4 v = *(const f32x4*)(smax + (size_t)b * C_ + tid * 4);
    float m = fmaxf(fmaxf(v.x, v.y), fmaxf(v.z, v.w));
    #pragma unroll
    for (int d = 1; d < 64; d <<= 1) m = fmaxf(m, __shfl_xor(m, d));
    if (lane == 0) red_s[w] = m;
    __syncthreads();
    m = fmaxf(fmaxf(red_s[0], red_s[1]), fmaxf(red_s[2], red_s[3]));

    f32x4 e;
    e.x = __expf(v.x - m); e.y = __expf(v.y - m);
    e.z = __expf(v.z - m); e.w = __expf(v.w - m);
    float s = e.x + e.y + e.z + e.w;
    #pragma unroll
    for (int d = 1; d < 64; d <<= 1) s += __shfl_xor(s, d);
    if (lane == 0) red_s[4 + w] = s;
    __syncthreads();
    s = red_s[4] + red_s[5] + red_s[6] + red_s[7];
    float inv = 1.f / s;
    *(f32x4*)&beta_s[tid * 4] = e * inv;
    __syncthreads();

    const float* cb = ctx + ((size_t)b * C_ + quad * 256) * H_ + tid;
    float acc = 0.f;
    #pragma unroll 8
    for (int i = 0; i < 256; ++i)
        acc += beta_s[quad * 256 + i] * cb[(size_t)i * H_];
    bpart[(size_t)bid * H_ + tid] = acc;
}

// ---------------- K3: out[:,3H:4H] = ctx * b_vec ---------------------------
__global__ __launch_bounds__(256) void k_colb(
    const float* __restrict__ ctx, const float* __restrict__ bpart,
    float* __restrict__ out)
{
    const int tid = threadIdx.x;
    const int bid = blockIdx.x;
    const int b = bid >> 8, cg = bid & 255;
    const int c = cg * 4 + (tid >> 6);
    const int h = (tid & 63) * 4;

    const float* bp = bpart + (size_t)b * 4 * H_ + h;
    f32x4 bv = *(const f32x4*)bp;
    bv += *(const f32x4*)(bp + H_);
    bv += *(const f32x4*)(bp + 2 * H_);
    bv += *(const f32x4*)(bp + 3 * H_);

    const size_t rowi = (size_t)b * C_ + c;
    f32x4 cv = *(const f32x4*)(ctx + rowi * H_ + h);
    *(f32x4*)(out + rowi * (4 * H_) + 3 * H_ + h) = cv * bv;
}

extern "C" void kernel_launch(void* const* d_in, const int* in_sizes, int n_in,
                              void* d_out, int out_size, void* d_ws, size_t ws_size,
                              hipStream_t stream) {
    const float* ctx  = (const float*)d_in[0];
    const float* qry  = (const float*)d_in[2];
    const float* attw = (const float*)d_in[4];
    const float* attb = (const float*)d_in[5];
    float* out = (float*)d_out;

    float* qdot  = (float*)d_ws;                  // B*Q      = 8192 f
    float* smax  = qdot + B_ * Q_;                // B*C      = 65536 f
    float* bpart = smax + B_ * C_;                // 256*H    = 65536 f
    short* qh    = (short*)(bpart + 256 * H_);    // B*Q*H bf16 = 4MB
    short* ql    = qh + (size_t)B_ * Q_ * H_;     // 4MB
    short* qT    = ql + (size_t)B_ * Q_ * H_;     // 4MB

    const size_t need = (size_t)(B_ * Q_ + B_ * C_ + 256 * H_) * 4
                      + (size_t)3 * B_ * Q_ * H_ * 2;

    if (ws_size >= need) {
        k_prep<<<B_ * 2, 256, 0, stream>>>(qry, attw, attb, qh, ql, qT, qdot);
        k_sim<<<B_ * 16, 256, 0, stream>>>(ctx, qh, ql, qT, attw, qdot, smax, out);
    } else {
        k_qdot<<<B_ * 32, 256, 0, stream>>>(qry, attw, attb, qdot);
        k_sim_v1<<<B_ * 16, 256, 0, stream>>>(ctx, qry, attw, qdot, smax, out);
    }
    k_beta<<<B_ * 4, 256, 0, stream>>>(ctx, smax, bpart);
    k_colb<<<B_ * 256, 256, 0, stream>>>(ctx, bpart, out);
}

// Round 8
// 418.320 us; speedup vs baseline: 1.0163x; 1.0163x over previous
//
#include <hip/hip_runtime.h>

#define B_ 64
#define C_ 1024
#define Q_ 128
#define H_ 256
#define NQ_ 16   // k_beta C-chunks per batch

typedef __attribute__((ext_vector_type(8))) short bfrag;   // 8 x bf16
typedef __attribute__((ext_vector_type(4))) float f32x4;

__device__ __forceinline__ short f2bf(float f) {
    union { float f; unsigned u; } v; v.f = f;
    unsigned u = v.u;
    unsigned r = u + 0x7fffu + ((u >> 16) & 1u);
    return (short)(r >> 16);
}
__device__ __forceinline__ float bf2f(short s) {
    union { float f; unsigned u; } v;
    v.u = ((unsigned)(unsigned short)s) << 16;
    return v.f;
}

// ---------------- K_prep: qh/ql bf16 [B,Q,H], qT bf16 [B,H,Q], qdot --------
__global__ __launch_bounds__(256) void k_prep(
    const float* __restrict__ qry, const float* __restrict__ attw,
    const float* __restrict__ attb,
    short* __restrict__ qh, short* __restrict__ ql, short* __restrict__ qT,
    float* __restrict__ qdot)
{
    __shared__ float wq_s[H_];
    __shared__ short t_s[64][80];
    const int tid = threadIdx.x;
    const int bid = blockIdx.x;          // 0..127
    const int b = bid >> 1;
    const int q0 = (bid & 1) * 64;
    wq_s[tid] = attw[H_ + tid];
    __syncthreads();

    const int rloc = tid >> 2;           // 0..63
    const int row = q0 + rloc;
    const int colseg = (tid & 3) * 16;
    const float* src_base = qry + ((size_t)b * Q_ + row) * H_;
    float qp = 0.f;

    for (int ct = 0; ct < 4; ++ct) {
        const int c0 = ct * 64;
        float tv[16];
        *(f32x4*)&tv[0]  = *(const f32x4*)(src_base + c0 + colseg);
        *(f32x4*)&tv[4]  = *(const f32x4*)(src_base + c0 + colseg + 4);
        *(f32x4*)&tv[8]  = *(const f32x4*)(src_base + c0 + colseg + 8);
        *(f32x4*)&tv[12] = *(const f32x4*)(src_base + c0 + colseg + 12);
        bfrag hv0, lv0, hv1, lv1;
        #pragma unroll
        for (int j = 0; j < 8; ++j) {
            qp += tv[j] * wq_s[c0 + colseg + j];
            short hi = f2bf(tv[j]);
            hv0[j] = hi; lv0[j] = f2bf(tv[j] - bf2f(hi));
        }
        #pragma unroll
        for (int j = 0; j < 8; ++j) {
            float t = tv[8 + j];
            qp += t * wq_s[c0 + colseg + 8 + j];
            short hi = f2bf(t);
            hv1[j] = hi; lv1[j] = f2bf(t - bf2f(hi));
        }
        short* qh_p = qh + ((size_t)b * Q_ + row) * H_ + c0 + colseg;
        *(bfrag*)qh_p = hv0; *(bfrag*)(qh_p + 8) = hv1;
        short* ql_p = ql + ((size_t)b * Q_ + row) * H_ + c0 + colseg;
        *(bfrag*)ql_p = lv0; *(bfrag*)(ql_p + 8) = lv1;
        #pragma unroll
        for (int j = 0; j < 8; ++j) {
            t_s[colseg + j][rloc] = hv0[j];
            t_s[colseg + 8 + j][rloc] = hv1[j];
        }
        __syncthreads();
        {
            const int hl = tid >> 2;         // 0..63
            const int qs = (tid & 3) * 16;
            bfrag tv2 = *(bfrag*)&t_s[hl][qs];
            bfrag tv3 = *(bfrag*)&t_s[hl][qs + 8];
            short* dst = &qT[((size_t)b * H_ + c0 + hl) * Q_ + q0 + qs];
            *(bfrag*)dst = tv2;
            *(bfrag*)(dst + 8) = tv3;
        }
        __syncthreads();
    }
    qp += __shfl_xor(qp, 1);
    qp += __shfl_xor(qp, 2);
    if ((tid & 3) == 0) qdot[b * Q_ + row] = qp + attb[0];
}

// ---------------- K0 (fallback): qdot -------------------------------------
__global__ __launch_bounds__(256) void k_qdot(
    const float* __restrict__ qry, const float* __restrict__ attw,
    const float* __restrict__ attb, float* __restrict__ qdot)
{
    const int tid = threadIdx.x, lane = tid & 63, w = tid >> 6;
    const int bid = blockIdx.x;
    const int b = bid >> 5, qg = bid & 31;
    const int q = qg * 4 + w;
    const float* src = qry + ((size_t)b * Q_ + q) * H_ + lane * 4;
    f32x4 v = *(const f32x4*)src;
    f32x4 wv = *(const f32x4*)(attw + H_ + lane * 4);
    float p = v.x * wv.x + v.y * wv.y + v.z * wv.z + v.w * wv.w;
    #pragma unroll
    for (int d = 1; d < 64; d <<= 1) p += __shfl_xor(p, d);
    if (lane == 0) qdot[b * Q_ + q] = p + attb[0];
}

#define SPAD 40    // k-slice row stride (32 + 8 pad)
#define PPAD 136   // P row stride (128 + 8 pad)
#define APAD 268   // a_s row stride (256 + 12 pad)

// ---------------- K1 fast: sim -> softmax -> a ; out cols 0..2, smax ------
__global__ __launch_bounds__(256) void k_sim(
    const float* __restrict__ ctx,
    const short* __restrict__ qh_g,
    const short* __restrict__ ql_g,
    const short* __restrict__ qT,
    const float* __restrict__ attw,
    const float* __restrict__ qdot,
    float* __restrict__ smax,
    float* __restrict__ out)
{
    __shared__ union SM {
        struct {
            short qh[Q_][SPAD];
            short ql[Q_][SPAD];
            short ch[64][SPAD];
            short cl[64][SPAD];
        } st;
        float a_s[16][APAD];
    } u;
    __shared__ short P_s[64][PPAD];
    __shared__ float wm_s[H_];
    __shared__ float wc_s[H_];
    __shared__ float qd_s[Q_];
    __shared__ float cdot_s[64];

    const int tid = threadIdx.x;
    const int lane = tid & 63;
    const int w = tid >> 6;
    const int bid = blockIdx.x;
    const int b = bid >> 4;
    const int c0 = (bid & 15) * 64;

    wc_s[tid] = attw[tid];
    wm_s[tid] = attw[2 * H_ + tid];
    if (tid < Q_) qd_s[tid] = qdot[b * Q_ + tid];
    __syncthreads();

    const int r16 = lane & 15;
    const int kp  = lane >> 4;

    f32x4 acc[8];
    #pragma unroll
    for (int t = 0; t < 8; ++t) acc[t] = (f32x4)(0.f);

    float cdp = 0.f;

    const int crow = tid >> 2;          // 0..63
    const int ckof = (tid & 3) * 8;     // 0,8,16,24
    const int qrow = tid >> 1;          // 0..127
    const int qkof = (tid & 1) * 16;    // 0,16

    const float* ctxb = ctx + ((size_t)b * C_ + c0) * H_;
    const short* qhb = qh_g + (size_t)b * Q_ * H_;
    const short* qlb = ql_g + (size_t)b * Q_ * H_;

    // ---- register prefetch of slice 0 ----
    f32x4 cv0 = *(const f32x4*)(ctxb + crow * H_ + ckof);
    f32x4 cv1 = *(const f32x4*)(ctxb + crow * H_ + ckof + 4);
    bfrag pqh0 = *(const bfrag*)&qhb[qrow * H_ + qkof];
    bfrag pqh1 = *(const bfrag*)&qhb[qrow * H_ + qkof + 8];
    bfrag pql0 = *(const bfrag*)&qlb[qrow * H_ + qkof];
    bfrag pql1 = *(const bfrag*)&qlb[qrow * H_ + qkof + 8];

    #pragma unroll
    for (int k0 = 0; k0 < H_; k0 += 32) {
        // ---- convert + LDS write from prefetched regs ----
        {
            float tv[8];
            *(f32x4*)&tv[0] = cv0;
            *(f32x4*)&tv[4] = cv1;
            bfrag hv, lv;
            #pragma unroll
            for (int j = 0; j < 8; ++j) {
                int k = k0 + ckof + j;
                cdp += tv[j] * wc_s[k];
                float cm = tv[j] * wm_s[k];
                short hi = f2bf(cm);
                hv[j] = hi;
                lv[j] = f2bf(cm - bf2f(hi));
            }
            *(bfrag*)&u.st.ch[crow][ckof] = hv;
            *(bfrag*)&u.st.cl[crow][ckof] = lv;
            *(bfrag*)&u.st.qh[qrow][qkof]     = pqh0;
            *(bfrag*)&u.st.qh[qrow][qkof + 8] = pqh1;
            *(bfrag*)&u.st.ql[qrow][qkof]     = pql0;
            *(bfrag*)&u.st.ql[qrow][qkof + 8] = pql1;
        }
        __syncthreads();
        // ---- issue next-slice global loads (latency hidden under MFMA) ----
        const int kn = k0 + 32;
        if (kn < H_) {
            cv0 = *(const f32x4*)(ctxb + crow * H_ + kn + ckof);
            cv1 = *(const f32x4*)(ctxb + crow * H_ + kn + ckof + 4);
            pqh0 = *(const bfrag*)&qhb[qrow * H_ + kn + qkof];
            pqh1 = *(const bfrag*)&qhb[qrow * H_ + kn + qkof + 8];
            pql0 = *(const bfrag*)&qlb[qrow * H_ + kn + qkof];
            pql1 = *(const bfrag*)&qlb[qrow * H_ + kn + qkof + 8];
        }
        // ---- MFMA: sim tiles (hh + lh + hl) ----
        bfrag a_hi = *(bfrag*)&u.st.ch[w * 16 + r16][kp * 8];
        bfrag a_lo = *(bfrag*)&u.st.cl[w * 16 + r16][kp * 8];
        #pragma unroll
        for (int t = 0; t < 8; ++t) {
            bfrag b_hi = *(bfrag*)&u.st.qh[t * 16 + r16][kp * 8];
            bfrag b_lo = *(bfrag*)&u.st.ql[t * 16 + r16][kp * 8];
            acc[t] = __builtin_amdgcn_mfma_f32_16x16x32_bf16(a_hi, b_hi, acc[t], 0, 0, 0);
            acc[t] = __builtin_amdgcn_mfma_f32_16x16x32_bf16(a_lo, b_hi, acc[t], 0, 0, 0);
            acc[t] = __builtin_amdgcn_mfma_f32_16x16x32_bf16(a_hi, b_lo, acc[t], 0, 0, 0);
        }
        __syncthreads();
    }

    // ---- cdot reduce ----
    {
        float cv = cdp;
        cv += __shfl_xor(cv, 1);
        cv += __shfl_xor(cv, 2);
        if ((lane & 3) == 0) cdot_s[crow] = cv;
    }
    __syncthreads();

    // ---- softmax over q ----
    float qdv[8];
    #pragma unroll
    for (int t = 0; t < 8; ++t) qdv[t] = qd_s[t * 16 + r16];
    float cdv[4];
    #pragma unroll
    for (int r = 0; r < 4; ++r) cdv[r] = cdot_s[w * 16 + kp * 4 + r];

    #pragma unroll
    for (int r = 0; r < 4; ++r) {
        float ev[8];
        float m = -1e30f;
        #pragma unroll
        for (int t = 0; t < 8; ++t) {
            float s = acc[t][r] + cdv[r] + qdv[t];
            ev[t] = s;
            m = fmaxf(m, s);
        }
        m = fmaxf(m, __shfl_xor(m, 1));
        m = fmaxf(m, __shfl_xor(m, 2));
        m = fmaxf(m, __shfl_xor(m, 4));
        m = fmaxf(m, __shfl_xor(m, 8));
        float ssum = 0.f;
        #pragma unroll
        for (int t = 0; t < 8; ++t) {
            float e = __expf(ev[t] - m);
            ev[t] = e;
            ssum += e;
        }
        ssum += __shfl_xor(ssum, 1);
        ssum += __shfl_xor(ssum, 2);
        ssum += __shfl_xor(ssum, 4);
        ssum += __shfl_xor(ssum, 8);
        const int rr = w * 16 + kp * 4 + r;
        if (r16 == 0) smax[(size_t)b * C_ + c0 + rr] = m;
        float inv = 1.f / ssum;
        #pragma unroll
        for (int t = 0; t < 8; ++t)
            P_s[rr][t * 16 + r16] = f2bf(ev[t] * inv);
    }
    __syncthreads();

    // ---- a = P @ query, B-frags from precomputed qT (bf16, 16B loads) ----
    f32x4 a2[4][4];
    #pragma unroll
    for (int m = 0; m < 4; ++m)
        #pragma unroll
        for (int i = 0; i < 4; ++i) a2[m][i] = (f32x4)(0.f);

    const int h0w = w * 64;
    const short* qTb = qT + (size_t)b * H_ * Q_;
    #pragma unroll
    for (int kq = 0; kq < 4; ++kq) {
        bfrag ap[4];
        #pragma unroll
        for (int m = 0; m < 4; ++m)
            ap[m] = *(bfrag*)&P_s[m * 16 + r16][kq * 32 + kp * 8];
        #pragma unroll
        for (int i = 0; i < 4; ++i) {
            bfrag bq = *(const bfrag*)&qTb[(size_t)(h0w + i * 16 + r16) * Q_ + kq * 32 + kp * 8];
            #pragma unroll
            for (int m = 0; m < 4; ++m)
                a2[m][i] = __builtin_amdgcn_mfma_f32_16x16x32_bf16(ap[m], bq, a2[m][i], 0, 0, 0);
        }
    }

    // ---- epilogue via LDS bounce, coalesced f32x4 stores, 4 quarters ----
    #pragma unroll
    for (int m = 0; m < 4; ++m) {
        #pragma unroll
        for (int i = 0; i < 4; ++i)
            #pragma unroll
            for (int r = 0; r < 4; ++r)
                u.a_s[kp * 4 + r][w * 64 + i * 16 + r16] = a2[m][i][r];
        __syncthreads();
        {
            const int row = tid >> 4;        // 0..15
            const int seg = tid & 15;        // h = seg*16
            const int cl = m * 16 + row;
            const size_t orow = ((size_t)b * C_ + c0 + cl) * (4 * H_);
            const float* cp = ctxb + (size_t)cl * H_ + seg * 16;
            float* op = out + orow + seg * 16;
            #pragma unroll
            for (int k2 = 0; k2 < 4; ++k2) {
                f32x4 cvx = *(const f32x4*)(cp + k2 * 4);
                f32x4 av = *(const f32x4*)&u.a_s[row][seg * 16 + k2 * 4];
                *(f32x4*)(op + k2 * 4) = cvx;
                *(f32x4*)(op + H_ + k2 * 4) = av;
                *(f32x4*)(op + 2 * H_ + k2 * 4) = cvx * av;
            }
        }
        __syncthreads();
    }
}

// ---------------- K1 fallback (round-1 version, fp32 inputs) ---------------
__global__ __launch_bounds__(256) void k_sim_v1(
    const float* __restrict__ ctx, const float* __restrict__ qry,
    const float* __restrict__ attw, const float* __restrict__ qdot,
    float* __restrict__ smax, float* __restrict__ out)
{
    __shared__ float wm_s[H_];
    __shared__ float wc_s[H_];
    __shared__ float qd_s[Q_];
    __shared__ float cdot_s[64];
    __shared__ short qh_s[Q_][SPAD];
    __shared__ short ql_s[Q_][SPAD];
    __shared__ short ch_s[64][SPAD];
    __shared__ short cl_s[64][SPAD];
    __shared__ short P_s[64][PPAD];

    const int tid = threadIdx.x;
    const int lane = tid & 63;
    const int w = tid >> 6;
    const int bid = blockIdx.x;
    const int b = bid >> 4;
    const int c0 = (bid & 15) * 64;

    wc_s[tid] = attw[tid];
    wm_s[tid] = attw[2 * H_ + tid];
    if (tid < Q_) qd_s[tid] = qdot[b * Q_ + tid];
    __syncthreads();

    const int r16 = lane & 15;
    const int kp  = lane >> 4;

    f32x4 acc[8];
    #pragma unroll
    for (int t = 0; t < 8; ++t) acc[t] = (f32x4)(0.f);
    float cdp = 0.f;
    const int crow = tid >> 2, ckof = (tid & 3) * 8;
    const int qrow = tid >> 1, qkof = (tid & 1) * 16;
    const float* ctxb = ctx + ((size_t)b * C_ + c0) * H_;
    const float* qryb = qry + (size_t)b * Q_ * H_;

    for (int k0 = 0; k0 < H_; k0 += 32) {
        {
            const float* src = ctxb + crow * H_ + k0 + ckof;
            f32x4 v0 = *(const f32x4*)(src);
            f32x4 v1 = *(const f32x4*)(src + 4);
            float tv[8];
            *(f32x4*)&tv[0] = v0; *(f32x4*)&tv[4] = v1;
            bfrag hv, lv;
            #pragma unroll
            for (int j = 0; j < 8; ++j) {
                int k = k0 + ckof + j;
                cdp += tv[j] * wc_s[k];
                float cm = tv[j] * wm_s[k];
                short hi = f2bf(cm);
                hv[j] = hi; lv[j] = f2bf(cm - bf2f(hi));
            }
            *(bfrag*)&ch_s[crow][ckof] = hv;
            *(bfrag*)&cl_s[crow][ckof] = lv;
        }
        {
            const float* src = qryb + qrow * H_ + k0 + qkof;
            float tv[16];
            *(f32x4*)&tv[0]  = *(const f32x4*)(src);
            *(f32x4*)&tv[4]  = *(const f32x4*)(src + 4);
            *(f32x4*)&tv[8]  = *(const f32x4*)(src + 8);
            *(f32x4*)&tv[12] = *(const f32x4*)(src + 12);
            bfrag h0v, l0v, h1v, l1v;
            #pragma unroll
            for (int j = 0; j < 8; ++j) {
                short hi = f2bf(tv[j]);
                h0v[j] = hi; l0v[j] = f2bf(tv[j] - bf2f(hi));
            }
            #pragma unroll
            for (int j = 0; j < 8; ++j) {
                short hi = f2bf(tv[8 + j]);
                h1v[j] = hi; l1v[j] = f2bf(tv[8 + j] - bf2f(hi));
            }
            *(bfrag*)&qh_s[qrow][qkof]     = h0v;
            *(bfrag*)&ql_s[qrow][qkof]     = l0v;
            *(bfrag*)&qh_s[qrow][qkof + 8] = h1v;
            *(bfrag*)&ql_s[qrow][qkof + 8] = l1v;
        }
        __syncthreads();
        bfrag a_hi = *(bfrag*)&ch_s[w * 16 + r16][kp * 8];
        bfrag a_lo = *(bfrag*)&cl_s[w * 16 + r16][kp * 8];
        #pragma unroll
        for (int t = 0; t < 8; ++t) {
            bfrag b_hi = *(bfrag*)&qh_s[t * 16 + r16][kp * 8];
            bfrag b_lo = *(bfrag*)&ql_s[t * 16 + r16][kp * 8];
            acc[t] = __builtin_amdgcn_mfma_f32_16x16x32_bf16(a_hi, b_hi, acc[t], 0, 0, 0);
            acc[t] = __builtin_amdgcn_mfma_f32_16x16x32_bf16(a_lo, b_hi, acc[t], 0, 0, 0);
            acc[t] = __builtin_amdgcn_mfma_f32_16x16x32_bf16(a_hi, b_lo, acc[t], 0, 0, 0);
        }
        __syncthreads();
    }
    {
        float cv = cdp;
        cv += __shfl_xor(cv, 1);
        cv += __shfl_xor(cv, 2);
        if ((lane & 3) == 0) cdot_s[crow] = cv;
    }
    __syncthreads();
    float qdv[8];
    #pragma unroll
    for (int t = 0; t < 8; ++t) qdv[t] = qd_s[t * 16 + r16];
    float cdv[4];
    #pragma unroll
    for (int r = 0; r < 4; ++r) cdv[r] = cdot_s[w * 16 + kp * 4 + r];
    #pragma unroll
    for (int r = 0; r < 4; ++r) {
        float ev[8];
        float m = -1e30f;
        #pragma unroll
        for (int t = 0; t < 8; ++t) {
            float s = acc[t][r] + cdv[r] + qdv[t];
            ev[t] = s; m = fmaxf(m, s);
        }
        m = fmaxf(m, __shfl_xor(m, 1));
        m = fmaxf(m, __shfl_xor(m, 2));
        m = fmaxf(m, __shfl_xor(m, 4));
        m = fmaxf(m, __shfl_xor(m, 8));
        float ssum = 0.f;
        #pragma unroll
        for (int t = 0; t < 8; ++t) {
            float e = __expf(ev[t] - m);
            ev[t] = e; ssum += e;
        }
        ssum += __shfl_xor(ssum, 1);
        ssum += __shfl_xor(ssum, 2);
        ssum += __shfl_xor(ssum, 4);
        ssum += __shfl_xor(ssum, 8);
        const int rr = w * 16 + kp * 4 + r;
        if (r16 == 0) smax[(size_t)b * C_ + c0 + rr] = m;
        float inv = 1.f / ssum;
        #pragma unroll
        for (int t = 0; t < 8; ++t)
            P_s[rr][t * 16 + r16] = f2bf(ev[t] * inv);
    }
    __syncthreads();
    f32x4 a2[4][4];
    #pragma unroll
    for (int m = 0; m < 4; ++m)
        #pragma unroll
        for (int i = 0; i < 4; ++i) a2[m][i] = (f32x4)(0.f);
    const int h0w = w * 64;
    for (int kq = 0; kq < 4; ++kq) {
        bfrag ap[4];
        #pragma unroll
        for (int m = 0; m < 4; ++m)
            ap[m] = *(bfrag*)&P_s[m * 16 + r16][kq * 32 + kp * 8];
        #pragma unroll
        for (int i = 0; i < 4; ++i) {
            const float* qc = qryb + (size_t)(kq * 32 + kp * 8) * H_ + h0w + i * 16 + r16;
            bfrag bq;
            #pragma unroll
            for (int j = 0; j < 8; ++j) bq[j] = f2bf(qc[(size_t)j * H_]);
            #pragma unroll
            for (int m = 0; m < 4; ++m)
                a2[m][i] = __builtin_amdgcn_mfma_f32_16x16x32_bf16(ap[m], bq, a2[m][i], 0, 0, 0);
        }
    }
    #pragma unroll
    for (int m = 0; m < 4; ++m) {
        #pragma unroll
        for (int r = 0; r < 4; ++r) {
            const int cl = m * 16 + kp * 4 + r;
            const size_t orow = ((size_t)b * C_ + c0 + cl) * (4 * H_);
            const float* crow_p = ctxb + (size_t)cl * H_;
            #pragma unroll
            for (int i = 0; i < 4; ++i) {
                const int h = h0w + i * 16 + r16;
                float av = a2[m][i][r];
                float cvx = crow_p[h];
                out[orow + h] = cvx;
                out[orow + H_ + h] = av;
                out[orow + 2 * H_ + h] = cvx * av;
            }
        }
    }
}

// ---------------- K2 fast: beta softmax + partial b_vec (16 chunks) --------
__global__ __launch_bounds__(256) void k_beta16(
    const float* __restrict__ ctx, const float* __restrict__ smax,
    float* __restrict__ bpart)   // [B*NQ_, H]
{
    __shared__ float beta_s[C_];
    __shared__ float red_s[8];
    const int tid = threadIdx.x, lane = tid & 63, w = tid >> 6;
    const int bid = blockIdx.x;      // 0..B*NQ_-1
    const int b = bid >> 4, quad = bid & (NQ_ - 1);

    f32x4 v = *(const f32x4*)(smax + (size_t)b * C_ + tid * 4);
    float m = fmaxf(fmaxf(v.x, v.y), fmaxf(v.z, v.w));
    #pragma unroll
    for (int d = 1; d < 64; d <<= 1) m = fmaxf(m, __shfl_xor(m, d));
    if (lane == 0) red_s[w] = m;
    __syncthreads();
    m = fmaxf(fmaxf(red_s[0], red_s[1]), fmaxf(red_s[2], red_s[3]));

    f32x4 e;
    e.x = __expf(v.x - m); e.y = __expf(v.y - m);
    e.z = __expf(v.z - m); e.w = __expf(v.w - m);
    float s = e.x + e.y + e.z + e.w;
    #pragma unroll
    for (int d = 1; d < 64; d <<= 1) s += __shfl_xor(s, d);
    if (lane == 0) red_s[4 + w] = s;
    __syncthreads();
    s = red_s[4] + red_s[5] + red_s[6] + red_s[7];
    float inv = 1.f / s;
    *(f32x4*)&beta_s[tid * 4] = e * inv;
    __syncthreads();

    // partial b_vec over 64 rows, h = tid; 16 chunks -> 1024 blocks (4/CU)
    const int rows = C_ / NQ_;   // 64
    const float* cb = ctx + ((size_t)b * C_ + quad * rows) * H_ + tid;
    float acc = 0.f;
    #pragma unroll 16
    for (int i = 0; i < rows; ++i)
        acc += beta_s[quad * rows + i] * cb[(size_t)i * H_];
    bpart[(size_t)bid * H_ + tid] = acc;
}

// ---------------- K2b: reduce bpart -> bvec [B,H] --------------------------
__global__ __launch_bounds__(256) void k_bvec(
    const float* __restrict__ bpart, float* __restrict__ bvec)
{
    const int b = blockIdx.x, tid = threadIdx.x;
    float s = 0.f;
    #pragma unroll
    for (int q = 0; q < NQ_; ++q)
        s += bpart[((size_t)b * NQ_ + q) * H_ + tid];
    bvec[(size_t)b * H_ + tid] = s;
}

// ---------------- K3 fast: out[:,3H:4H] = ctx * b_vec ----------------------
__global__ __launch_bounds__(256) void k_colb2(
    const float* __restrict__ ctx, const float* __restrict__ bvec,
    float* __restrict__ out)
{
    const int tid = threadIdx.x;
    const int bid = blockIdx.x;
    const int b = bid >> 8, cg = bid & 255;
    const int c = cg * 4 + (tid >> 6);
    const int h = (tid & 63) * 4;

    f32x4 bv = *(const f32x4*)(bvec + (size_t)b * H_ + h);
    const size_t rowi = (size_t)b * C_ + c;
    f32x4 cv = *(const f32x4*)(ctx + rowi * H_ + h);
    *(f32x4*)(out + rowi * (4 * H_) + 3 * H_ + h) = cv * bv;
}

// ---------------- K2/K3 fallback (4-quad originals) ------------------------
__global__ __launch_bounds__(256) void k_beta4(
    const float* __restrict__ ctx, const float* __restrict__ smax,
    float* __restrict__ bpart)
{
    __shared__ float beta_s[C_];
    __shared__ float red_s[8];
    const int tid = threadIdx.x, lane = tid & 63, w = tid >> 6;
    const int bid = blockIdx.x;
    const int b = bid >> 2, quad = bid & 3;

    f32x4 v = *(const f32x4*)(smax + (size_t)b * C_ + tid * 4);
    float m = fmaxf(fmaxf(v.x, v.y), fmaxf(v.z, v.w));
    #pragma unroll
    for (int d = 1; d < 64; d <<= 1) m = fmaxf(m, __shfl_xor(m, d));
    if (lane == 0) red_s[w] = m;
    __syncthreads();
    m = fmaxf(fmaxf(red_s[0], red_s[1]), fmaxf(red_s[2], red_s[3]));

    f32x4 e;
    e.x = __expf(v.x - m); e.y = __expf(v.y - m);
    e.z = __expf(v.z - m); e.w = __expf(v.w - m);
    float s = e.x + e.y + e.z + e.w;
    #pragma unroll
    for (int d = 1; d < 64; d <<= 1) s += __shfl_xor(s, d);
    if (lane == 0) red_s[4 + w] = s;
    __syncthreads();
    s = red_s[4] + red_s[5] + red_s[6] + red_s[7];
    float inv = 1.f / s;
    *(f32x4*)&beta_s[tid * 4] = e * inv;
    __syncthreads();

    const float* cb = ctx + ((size_t)b * C_ + quad * 256) * H_ + tid;
    float acc = 0.f;
    #pragma unroll 8
    for (int i = 0; i < 256; ++i)
        acc += beta_s[quad * 256 + i] * cb[(size_t)i * H_];
    bpart[(size_t)bid * H_ + tid] = acc;
}

__global__ __launch_bounds__(256) void k_colb4(
    const float* __restrict__ ctx, const float* __restrict__ bpart,
    float* __restrict__ out)
{
    const int tid = threadIdx.x;
    const int bid = blockIdx.x;
    const int b = bid >> 8, cg = bid & 255;
    const int c = cg * 4 + (tid >> 6);
    const int h = (tid & 63) * 4;

    const float* bp = bpart + (size_t)b * 4 * H_ + h;
    f32x4 bv = *(const f32x4*)bp;
    bv += *(const f32x4*)(bp + H_);
    bv += *(const f32x4*)(bp + 2 * H_);
    bv += *(const f32x4*)(bp + 3 * H_);

    const size_t rowi = (size_t)b * C_ + c;
    f32x4 cv = *(const f32x4*)(ctx + rowi * H_ + h);
    *(f32x4*)(out + rowi * (4 * H_) + 3 * H_ + h) = cv * bv;
}

extern "C" void kernel_launch(void* const* d_in, const int* in_sizes, int n_in,
                              void* d_out, int out_size, void* d_ws, size_t ws_size,
                              hipStream_t stream) {
    const float* ctx  = (const float*)d_in[0];
    const float* qry  = (const float*)d_in[2];
    const float* attw = (const float*)d_in[4];
    const float* attb = (const float*)d_in[5];
    float* out = (float*)d_out;

    float* qdot  = (float*)d_ws;                      // B*Q
    float* smax  = qdot + B_ * Q_;                    // B*C
    float* bpart = smax + B_ * C_;                    // B*NQ_*H (1 MB)
    float* bvec  = bpart + (size_t)B_ * NQ_ * H_;     // B*H
    short* qh    = (short*)(bvec + B_ * H_);          // B*Q*H bf16
    short* ql    = qh + (size_t)B_ * Q_ * H_;
    short* qT    = ql + (size_t)B_ * Q_ * H_;

    const size_t need_fast = (size_t)(B_ * Q_ + B_ * C_ + B_ * NQ_ * H_ + B_ * H_) * 4
                           + (size_t)3 * B_ * Q_ * H_ * 2;

    if (ws_size >= need_fast) {
        k_prep<<<B_ * 2, 256, 0, stream>>>(qry, attw, attb, qh, ql, qT, qdot);
        k_sim<<<B_ * 16, 256, 0, stream>>>(ctx, qh, ql, qT, attw, qdot, smax, out);
        k_beta16<<<B_ * NQ_, 256, 0, stream>>>(ctx, smax, bpart);
        k_bvec<<<B_, 256, 0, stream>>>(bpart, bvec);
        k_colb2<<<B_ * 256, 256, 0, stream>>>(ctx, bvec, out);
    } else {
        k_qdot<<<B_ * 32, 256, 0, stream>>>(qry, attw, attb, qdot);
        k_sim_v1<<<B_ * 16, 256, 0, stream>>>(ctx, qry, attw, qdot, smax, out);
        k_beta4<<<B_ * 4, 256, 0, stream>>>(ctx, smax, bpart);
        k_colb4<<<B_ * 256, 256, 0, stream>>>(ctx, bpart, out);
    }
}